// Round 14
// baseline (590.814 us; speedup 1.0000x reference)
//
#include <hip/hip_runtime.h>

// Bidirectional LSTM, B=256, T=1024, V=6, D=64, U=64; out = last-step
// concat(h_f, h_b) @ Wd + bd, shape (B,1).
// Reductions: backward dir = ONE step from h0=0 (Wr_b dead); V=6 -> xproj
// table; mask = 6-bit scalar.
// R8..R13 (4-wave quad structure) plateaued at ~297us, LATENCY-PINNED:
// R13 cut VALU issue 18 cyc -> wall unchanged. The pin is the cross-wave
// h-exchange (write -> __syncthreads -> 120cyc LDS read) + reduce/act chain.
// R14: BARRIER-FREE single-wave recurrence. 1 wave = 1 batch, lane = unit:
//  - lane computes all 4 of its unit's gate dots (256 MAC) -> no DPP reduce,
//    no broadcast, no quad redundancy;
//  - h exchange intra-wave via LDS (DS pipe is in-order per wave: write then
//    read needs no barrier). ZERO __syncthreads in the 1024-step loop;
//  - h reads = 8 UNIFORM-address ds_read_b128 (broadcast, conflict-free);
//  - MACs as 128 inline-asm v_pk_fma_f16 (VOP3P; clang scalarized the v2h
//    fma in R13 -> pk never emitted; pk f16 is the 2x-f16-peak path);
//  - proj: per-lane float4 (4 gates) = 1 ds_read_b128/step, prefetch depth 1;
//    tokens scalar pipeline depth 2.
// 4 batches/block (4 waves, grid 64): setup shared, main loops independent.

constexpr int kB = 256;
constexpr int kT = 1024;
constexpr int kV = 6;
constexpr int kD = 64;
constexpr int kU = 64;
constexpr int kG = 256; // 4*U gate columns

#define LOG2E 1.44269504f

typedef _Float16 v2h __attribute__((ext_vector_type(2)));

__device__ __forceinline__ float fast_rcp(float x) { return __builtin_amdgcn_rcpf(x); }
__device__ __forceinline__ float exp2_f(float x)   { return __builtin_amdgcn_exp2f(x); }
__device__ __forceinline__ float sig_f(float z)  { return fast_rcp(1.0f + exp2_f(-LOG2E * z)); }
__device__ __forceinline__ float tanh_f(float z) { return 2.0f * fast_rcp(1.0f + exp2_f(-2.0f * LOG2E * z)) - 1.0f; }

__device__ __forceinline__ v2h as_v2h(float x) { return __builtin_bit_cast(v2h, x); }

// forced VOP3P packed f16 (v2h = 4B = one VGPR)
__device__ __forceinline__ v2h pk_mul(v2h a, v2h b) {
    v2h d;
    asm("v_pk_mul_f16 %0, %1, %2" : "=v"(d) : "v"(a), "v"(b));
    return d;
}
__device__ __forceinline__ void pk_fma(v2h& acc, v2h a, v2h b) {
    asm("v_pk_fma_f16 %0, %1, %2, %0" : "+v"(acc) : "v"(a), "v"(b));
}

__global__ __launch_bounds__(256, 1) void bilstm_last_kernel(
    const int*   __restrict__ tokens, // (B,T)
    const float* __restrict__ emb,    // (6,64)
    const float* __restrict__ Wk_f,   // (64,256)
    const float* __restrict__ Wr_f,   // (64,256)
    const float* __restrict__ b_f,    // (256)
    const float* __restrict__ Wk_b,   // (64,256)
    const float* __restrict__ b_b,    // (256)
    const float* __restrict__ Wd,     // (128)
    const float* __restrict__ bd,     // (1)
    float*       __restrict__ out)    // (B)
{
    __shared__ float s_emb[kV * kD];
    __shared__ float s_projQ[kV * kG];             // [v][u][g] float4-per-unit
    __shared__ int   s_tok4[4][kT];                // per-batch token streams
    __shared__ _Float16 __align__(8) s_hh[4][kU];  // per-batch h (f16), no dbuf
    __shared__ float s_actb[4 * kG];               // bwd-step scratch
    __shared__ float s_hbv[4 * kU];                // bwd h per batch

    const int tid = threadIdx.x;
    const int l   = tid & 63;       // lane
    const int bi  = tid >> 6;       // wave id == batch-within-block
    const int b0  = blockIdx.x * 4;
    const int u   = l;              // unit owned by this lane

    // ---- stage emb + own batch's tokens (per wave, coalesced) ----
    for (int i = tid; i < kV * kD; i += 256) s_emb[i] = emb[i];
#pragma unroll
    for (int r = 0; r < 4; ++r)
        ((int4*)s_tok4[bi])[l + 64 * r] =
            ((const int4*)(tokens + (b0 + bi) * kT))[l + 64 * r];
    __syncthreads();

    // ---- 6-bit mask, scalarized: bit v = any(emb[v][:] != 0) ----
    unsigned int mbv = 0;
#pragma unroll
    for (int v = 0; v < kV; ++v) {
        const unsigned long long bb = __ballot(s_emb[v * kD + l] != 0.0f);
        mbv |= (bb != 0ull) ? (1u << v) : 0u;
    }
    const unsigned int smb = __builtin_amdgcn_readfirstlane(mbv);

    const int tokL0 = s_tok4[0][kT - 1];
    const int tokL1 = s_tok4[1][kT - 1];
    const int tokL2 = s_tok4[2][kT - 1];
    const int tokL3 = s_tok4[3][kT - 1];

    // ---- proj table (column tid, coalesced), stored as [v][u][g] so lane u
    // later reads one float4 = proj for its 4 gates. Also bwd accb x4 batches.
    float a0 = b_f[tid], a1 = a0, a2 = a0, a3 = a0, a4 = a0, a5 = a0;
    float ab0 = b_b[tid], ab1 = ab0, ab2 = ab0, ab3 = ab0;
    for (int d = 0; d < kD; ++d) {
        const float wkf = Wk_f[d * kG + tid];
        const float wkb = Wk_b[d * kG + tid];
        a0 = fmaf(s_emb[0 * kD + d], wkf, a0);
        a1 = fmaf(s_emb[1 * kD + d], wkf, a1);
        a2 = fmaf(s_emb[2 * kD + d], wkf, a2);
        a3 = fmaf(s_emb[3 * kD + d], wkf, a3);
        a4 = fmaf(s_emb[4 * kD + d], wkf, a4);
        a5 = fmaf(s_emb[5 * kD + d], wkf, a5);
        ab0 = fmaf(s_emb[tokL0 * kD + d], wkb, ab0);
        ab1 = fmaf(s_emb[tokL1 * kD + d], wkb, ab1);
        ab2 = fmaf(s_emb[tokL2 * kD + d], wkb, ab2);
        ab3 = fmaf(s_emb[tokL3 * kD + d], wkb, ab3);
    }
    {   // column tid = g0*64 + u0  ->  projQ[v][u0][g0]
        const int g0 = tid >> 6, u0 = tid & 63;
        const int q = u0 * 4 + g0;
        s_projQ[0 * kG + q] = a0;
        s_projQ[1 * kG + q] = a1;
        s_projQ[2 * kG + q] = a2;
        s_projQ[3 * kG + q] = a3;
        s_projQ[4 * kG + q] = a4;
        s_projQ[5 * kG + q] = a5;
    }
    {   // bwd-step activations, 4 batches (column type: i/f sig, g tanh, o sig)
        float r0, r1, r2, r3;
        if (tid < 128)      { r0 = sig_f(ab0);  r1 = sig_f(ab1);  r2 = sig_f(ab2);  r3 = sig_f(ab3); }
        else if (tid < 192) { r0 = tanh_f(ab0); r1 = tanh_f(ab1); r2 = tanh_f(ab2); r3 = tanh_f(ab3); }
        else                { r0 = sig_f(ab0);  r1 = sig_f(ab1);  r2 = sig_f(ab2);  r3 = sig_f(ab3); }
        s_actb[0 * kG + tid] = r0;
        s_actb[1 * kG + tid] = r1;
        s_actb[2 * kG + tid] = r2;
        s_actb[3 * kG + tid] = r3;
    }
    __syncthreads();
    if (tid < kU) {
#pragma unroll
        for (int bb = 0; bb < 4; ++bb) {
            const float cb = s_actb[bb * kG + tid] * s_actb[bb * kG + 128 + tid];
            const float hb = s_actb[bb * kG + 192 + tid] * tanh_f(cb);
            const int tl = (bb == 0) ? tokL0 : (bb == 1) ? tokL1 : (bb == 2) ? tokL2 : tokL3;
            s_hbv[bb * kU + tid] = ((smb >> tl) & 1) ? hb : 0.0f;
        }
    }

    // ---- recurrent weights: 128 v2h regs: W[g][j] = Wr_f rows 2j,2j+1, col g*64+u
#define DECLW(g, j)                                                      \
    v2h W##g##_##j;                                                      \
    W##g##_##j.x = (_Float16)Wr_f[(2 * j + 0) * kG + (g * 64 + u)];      \
    W##g##_##j.y = (_Float16)Wr_f[(2 * j + 1) * kG + (g * 64 + u)];
#define DECLROW(g)                                                       \
    DECLW(g,0)  DECLW(g,1)  DECLW(g,2)  DECLW(g,3)                       \
    DECLW(g,4)  DECLW(g,5)  DECLW(g,6)  DECLW(g,7)                       \
    DECLW(g,8)  DECLW(g,9)  DECLW(g,10) DECLW(g,11)                      \
    DECLW(g,12) DECLW(g,13) DECLW(g,14) DECLW(g,15)                      \
    DECLW(g,16) DECLW(g,17) DECLW(g,18) DECLW(g,19)                      \
    DECLW(g,20) DECLW(g,21) DECLW(g,22) DECLW(g,23)                      \
    DECLW(g,24) DECLW(g,25) DECLW(g,26) DECLW(g,27)                      \
    DECLW(g,28) DECLW(g,29) DECLW(g,30) DECLW(g,31)
    DECLROW(0) DECLROW(1) DECLROW(2) DECLROW(3)
#undef DECLROW
#undef DECLW

    const v2h kOnes = {(_Float16)1.f, (_Float16)1.f};

    // ---- init own h (own-wave region; ordering by in-order DS pipe) ----
    s_hh[bi][u] = (_Float16)0.f;
    float c = 0.0f, hreg = 0.0f;
    __syncthreads();   // projQ + s_hbv + token stores visible to all

    // ---- scalar token pipeline (depth 2) + proj prefetch (depth 1) ----
    int stok0 = __builtin_amdgcn_readfirstlane(s_tok4[bi][0]);
    int stok1 = __builtin_amdgcn_readfirstlane(s_tok4[bi][1]);
    float4 pq = *(const float4*)&s_projQ[stok0 * kG + u * 4];  // proj[tok0] 4 gates

    // per gate: 2 chains of 16 pk (f16 acc) folded via dot2
#define MACG(g)                                                          \
        v2h A##g = pk_mul(HH0,  W##g##_0);                               \
        v2h B##g = pk_mul(HH16, W##g##_16);                              \
        pk_fma(A##g, HH1,  W##g##_1);   pk_fma(B##g, HH17, W##g##_17);   \
        pk_fma(A##g, HH2,  W##g##_2);   pk_fma(B##g, HH18, W##g##_18);   \
        pk_fma(A##g, HH3,  W##g##_3);   pk_fma(B##g, HH19, W##g##_19);   \
        pk_fma(A##g, HH4,  W##g##_4);   pk_fma(B##g, HH20, W##g##_20);   \
        pk_fma(A##g, HH5,  W##g##_5);   pk_fma(B##g, HH21, W##g##_21);   \
        pk_fma(A##g, HH6,  W##g##_6);   pk_fma(B##g, HH22, W##g##_22);   \
        pk_fma(A##g, HH7,  W##g##_7);   pk_fma(B##g, HH23, W##g##_23);   \
        pk_fma(A##g, HH8,  W##g##_8);   pk_fma(B##g, HH24, W##g##_24);   \
        pk_fma(A##g, HH9,  W##g##_9);   pk_fma(B##g, HH25, W##g##_25);   \
        pk_fma(A##g, HH10, W##g##_10);  pk_fma(B##g, HH26, W##g##_26);   \
        pk_fma(A##g, HH11, W##g##_11);  pk_fma(B##g, HH27, W##g##_27);   \
        pk_fma(A##g, HH12, W##g##_12);  pk_fma(B##g, HH28, W##g##_28);   \
        pk_fma(A##g, HH13, W##g##_13);  pk_fma(B##g, HH29, W##g##_29);   \
        pk_fma(A##g, HH14, W##g##_14);  pk_fma(B##g, HH30, W##g##_30);   \
        pk_fma(A##g, HH15, W##g##_15);  pk_fma(B##g, HH31, W##g##_31);   \
        const float z##g = __builtin_amdgcn_fdot2(A##g, kOnes, 0.0f, false) \
                         + __builtin_amdgcn_fdot2(B##g, kOnes, 0.0f, false);

    for (int t = 0; t < kT; ++t) {
        // reads first: 8 uniform-address b128 (h, broadcast) + tok + next proj
        const float4* hp = (const float4*)&s_hh[bi][0];
        const float4 h40 = hp[0], h41 = hp[1], h42 = hp[2], h43 = hp[3];
        const float4 h44 = hp[4], h45 = hp[5], h46 = hp[6], h47 = hp[7];
        const int   vtok2 = s_tok4[bi][(t + 2) & (kT - 1)];
        const float4 pqN  = *(const float4*)&s_projQ[stok1 * kG + u * 4];

        const v2h HH0  = as_v2h(h40.x), HH1  = as_v2h(h40.y), HH2  = as_v2h(h40.z), HH3  = as_v2h(h40.w);
        const v2h HH4  = as_v2h(h41.x), HH5  = as_v2h(h41.y), HH6  = as_v2h(h41.z), HH7  = as_v2h(h41.w);
        const v2h HH8  = as_v2h(h42.x), HH9  = as_v2h(h42.y), HH10 = as_v2h(h42.z), HH11 = as_v2h(h42.w);
        const v2h HH12 = as_v2h(h43.x), HH13 = as_v2h(h43.y), HH14 = as_v2h(h43.z), HH15 = as_v2h(h43.w);
        const v2h HH16 = as_v2h(h44.x), HH17 = as_v2h(h44.y), HH18 = as_v2h(h44.z), HH19 = as_v2h(h44.w);
        const v2h HH20 = as_v2h(h45.x), HH21 = as_v2h(h45.y), HH22 = as_v2h(h45.z), HH23 = as_v2h(h45.w);
        const v2h HH24 = as_v2h(h46.x), HH25 = as_v2h(h46.y), HH26 = as_v2h(h46.z), HH27 = as_v2h(h46.w);
        const v2h HH28 = as_v2h(h47.x), HH29 = as_v2h(h47.y), HH30 = as_v2h(h47.z), HH31 = as_v2h(h47.w);

        MACG(0) MACG(1) MACG(2) MACG(3)

        const float zi = z0 + pq.x;
        const float zf = z1 + pq.y;
        const float zg = z2 + pq.z;
        const float zo = z3 + pq.w;

        const float ai = sig_f(zi);
        const float af = sig_f(zf);
        const float ag = tanh_f(zg);
        const float ao = sig_f(zo);
        const float cn = fmaf(af, c, ai * ag);
        const float hn = ao * tanh_f(cn);
        if ((smb >> stok0) & 1) { c = cn; hreg = hn; }  // uniform branch

        s_hh[bi][u] = (_Float16)hreg;   // next iter's reads follow in pipe order

        stok0 = stok1;
        stok1 = __builtin_amdgcn_readfirstlane(vtok2);
        pq = pqN;
    }
#undef MACG

    // ---- epilogue (in-wave): out[b] = h.Wd[0:64] + hb.Wd[64:128] + bd ----
    {
        float v = hreg * Wd[u] + s_hbv[bi * kU + u] * Wd[kU + u];
#pragma unroll
        for (int off = 32; off > 0; off >>= 1) v += __shfl_down(v, off, 64);
        if (l == 0) out[b0 + bi] = v + bd[0];
    }
}

extern "C" void kernel_launch(void* const* d_in, const int* in_sizes, int n_in,
                              void* d_out, int out_size, void* d_ws, size_t ws_size,
                              hipStream_t stream) {
    const int*   tokens = (const int*)d_in[0];
    const float* emb    = (const float*)d_in[1];
    const float* Wk_f   = (const float*)d_in[2];
    const float* Wr_f   = (const float*)d_in[3];
    const float* b_f    = (const float*)d_in[4];
    const float* Wk_b   = (const float*)d_in[5];
    // d_in[6] = Wr_b: unused (backward runs one step from h0=0)
    const float* b_b    = (const float*)d_in[7];
    const float* Wd     = (const float*)d_in[8];
    const float* bd     = (const float*)d_in[9];
    float* out = (float*)d_out;

    bilstm_last_kernel<<<kB / 4, 256, 0, stream>>>(
        tokens, emb, Wk_f, Wr_f, b_f, Wk_b, b_b, Wd, bd, out);
}

// Round 15
// 346.778 us; speedup vs baseline: 1.7037x; 1.7037x over previous
//
#include <hip/hip_runtime.h>

// Bidirectional LSTM, B=256, T=1024, V=6, D=64, U=64; out = last-step
// concat(h_f, h_b) @ Wd + bd, shape (B,1).
// Reductions: backward dir = ONE step from h0=0 (Wr_b dead); V=6 -> xproj is
// a 6x256 table; mask = 6-bit scalar.
// History: R5 quad-slice+DPP (386) -> R6 own-gate act (348) -> R8 h-first
// (310) -> R12 f16 h-exchange + dot2 (296, BEST). R13 (-18 issue cyc) was
// NEUTRAL -> step is latency-pinned, not issue-pinned. R14 barrier-free
// 1-wave rewrite regressed (compiler refuses >~64 resident VGPRs/lane;
// per-step weight reloads). R15 = exact revert to R12.
// Step chain (~694 cyc): barrier drain/skew ~100 + ds_read h ~120 + issue
// ~250 + dep-chain stalls ~200 (dot2 chain, 2 transcendental chains, DPP).
// This is the structural floor of the 4-wave cross-exchange decomposition.

constexpr int kB = 256;
constexpr int kT = 1024;
constexpr int kV = 6;
constexpr int kD = 64;
constexpr int kU = 64;
constexpr int kG = 256; // 4*U gate columns

#define LOG2E 1.44269504f

typedef _Float16 v2h __attribute__((ext_vector_type(2)));

template <int CTRL>
__device__ __forceinline__ float dppf(float x) {
    return __int_as_float(
        __builtin_amdgcn_mov_dpp(__float_as_int(x), CTRL, 0xF, 0xF, true));
}
constexpr int kXor1 = 0xB1; // quad_perm(1,0,3,2)
constexpr int kXor2 = 0x4E; // quad_perm(2,3,0,1)
constexpr int kBc0 = 0x00, kBc1 = 0x55, kBc2 = 0xAA, kBc3 = 0xFF;

__device__ __forceinline__ float fast_rcp(float x) { return __builtin_amdgcn_rcpf(x); }
__device__ __forceinline__ float exp2_f(float x)   { return __builtin_amdgcn_exp2f(x); }
__device__ __forceinline__ float sig_f(float z)  { return fast_rcp(1.0f + exp2_f(-LOG2E * z)); }
__device__ __forceinline__ float tanh_f(float z) { return 2.0f * fast_rcp(1.0f + exp2_f(-2.0f * LOG2E * z)) - 1.0f; }

__device__ __forceinline__ v2h as_v2h(float x) { return __builtin_bit_cast(v2h, x); }

__global__ __launch_bounds__(256, 1) void bilstm_last_kernel(
    const int*   __restrict__ tokens, // (B,T)
    const float* __restrict__ emb,    // (6,64)
    const float* __restrict__ Wk_f,   // (64,256)
    const float* __restrict__ Wr_f,   // (64,256)
    const float* __restrict__ b_f,    // (256)
    const float* __restrict__ Wk_b,   // (64,256)
    const float* __restrict__ b_b,    // (256)
    const float* __restrict__ Wd,     // (128)
    const float* __restrict__ bd,     // (1)
    float*       __restrict__ out)    // (B)
{
    __shared__ float s_emb[kV * kD];
    __shared__ float s_projP[kV * kG];              // PERMUTED xproj_f table
    __shared__ int   s_tok[kT];
    __shared__ _Float16 __align__(16) s_hh[2][kU];  // double-buffered h (f16)
    __shared__ float s_act[kG];                     // scratch (bwd step + epilogue)

    const int b   = blockIdx.x;
    const int tid = threadIdx.x;
    const int l   = tid & 63;       // lane in wave
    const int wv  = tid >> 6;       // wave id 0..3
    const int s   = l & 3;          // h-slice AND owned gate (0..3 = i,f,g,o)
    const int k   = l >> 2;         // 0..15
    const int u   = wv * 16 + k;    // unit owned by this quad

    // ---- stage emb + tokens ----
    for (int i = tid; i < kV * kD; i += 256) s_emb[i] = emb[i];
    ((int4*)s_tok)[tid] = ((const int4*)(tokens + b * kT))[tid];
    if (tid < kU) { s_hh[0][tid] = (_Float16)0.f; s_hh[1][tid] = (_Float16)0.f; }
    __syncthreads();

    // ---- 6-bit mask, scalarized: bit v = any(emb[v][:] != 0) ----
    unsigned int mbv = 0;
#pragma unroll
    for (int v = 0; v < kV; ++v) {
        const unsigned long long bb = __ballot(s_emb[v * kD + l] != 0.0f);
        mbv |= (bb != 0ull) ? (1u << v) : 0u;
    }
    const unsigned int smb = __builtin_amdgcn_readfirstlane(mbv);

    const int tokL = s_tok[kT - 1];

    // ---- proj table (coalesced global reads per column tid), stored PERMUTED
    // so lane q of the step loop reads proj[v][ (q&3)*64 + u(q) ] at
    // s_projP[v*256+q].
    float a0 = b_f[tid], a1 = a0, a2 = a0, a3 = a0, a4 = a0, a5 = a0;
    float accb = b_b[tid];
    for (int d = 0; d < kD; ++d) {
        const float wkf = Wk_f[d * kG + tid];
        const float wkb = Wk_b[d * kG + tid];
        a0 = fmaf(s_emb[0 * kD + d], wkf, a0);
        a1 = fmaf(s_emb[1 * kD + d], wkf, a1);
        a2 = fmaf(s_emb[2 * kD + d], wkf, a2);
        a3 = fmaf(s_emb[3 * kD + d], wkf, a3);
        a4 = fmaf(s_emb[4 * kD + d], wkf, a4);
        a5 = fmaf(s_emb[5 * kD + d], wkf, a5);
        accb = fmaf(s_emb[tokL * kD + d], wkb, accb);
    }
    {   // inverse perm: lane q wanting column 'tid' is q = w0*64 + k0*4 + g0
        const int g0 = tid >> 6, u0 = tid & 63, w0 = u0 >> 4, k0 = u0 & 15;
        const int q = w0 * 64 + k0 * 4 + g0;
        s_projP[0 * kG + q] = a0;
        s_projP[1 * kG + q] = a1;
        s_projP[2 * kG + q] = a2;
        s_projP[3 * kG + q] = a3;
        s_projP[4 * kG + q] = a4;
        s_projP[5 * kG + q] = a5;
    }

    // ---- backward single step: z = xproj_b only (h0=0, c0=0 -> f dead) ----
    float ab;
    if (tid < 128)      ab = sig_f(accb);
    else if (tid < 192) ab = tanh_f(accb);
    else                ab = sig_f(accb);
    s_act[tid] = ab;
    __syncthreads();
    float hb_val = 0.0f;
    if (tid < kU) {
        const float cb = s_act[tid] * s_act[2 * kU + tid];
        const float hb = s_act[3 * kU + tid] * tanh_f(cb);
        hb_val = ((smb >> tokL) & 1) ? hb : 0.0f;
    }

    // ---- recurrent weights: f16 pairs, 8 v2h per gate (32 VGPRs total) ----
#define DECLH(g, p)                                                         \
    v2h wh##g##_##p;                                                        \
    wh##g##_##p.x = (_Float16)Wr_f[(16 * s + 2 * p + 0) * kG + (g * 64 + u)]; \
    wh##g##_##p.y = (_Float16)Wr_f[(16 * s + 2 * p + 1) * kG + (g * 64 + u)];
    DECLH(0,0) DECLH(0,1) DECLH(0,2) DECLH(0,3) DECLH(0,4) DECLH(0,5) DECLH(0,6) DECLH(0,7)
    DECLH(1,0) DECLH(1,1) DECLH(1,2) DECLH(1,3) DECLH(1,4) DECLH(1,5) DECLH(1,6) DECLH(1,7)
    DECLH(2,0) DECLH(2,1) DECLH(2,2) DECLH(2,3) DECLH(2,4) DECLH(2,5) DECLH(2,6) DECLH(2,7)
    DECLH(3,0) DECLH(3,1) DECLH(3,2) DECLH(3,3) DECLH(3,4) DECLH(3,5) DECLH(3,6) DECLH(3,7)
#undef DECLH

    // per-lane activation constants: gate s==2 is tanh, others sigmoid
    const bool  isg    = (s == 2);
    const float aScale = isg ? -2.0f * LOG2E : -LOG2E;
    const float aMul   = isg ? 2.0f : 1.0f;
    const float aAdd   = isg ? -1.0f : 0.0f;

    float c = 0.0f, hreg = 0.0f;
    __syncthreads();   // projP + s_hh init visible

    // ---- scalar token pipeline, depth 2 (through LDS) ----
    int stok0 = __builtin_amdgcn_readfirstlane(s_tok[0]);
    float zcur = s_projP[stok0 * kG + tid];   // own-gate proj for this lane
    int   mskc = (smb >> stok0) & 1;          // scalar
    int   stokA = __builtin_amdgcn_readfirstlane(s_tok[1]);

    // per gate: 8 dot2 in 2 chains of depth 4, then 1 add
#define DOTG(g)                                                               \
        float pa##g = __builtin_amdgcn_fdot2(H0, wh##g##_0, 0.0f, false);     \
        float pb##g = __builtin_amdgcn_fdot2(H1, wh##g##_1, 0.0f, false);     \
        pa##g = __builtin_amdgcn_fdot2(H2, wh##g##_2, pa##g, false);          \
        pb##g = __builtin_amdgcn_fdot2(H3, wh##g##_3, pb##g, false);          \
        pa##g = __builtin_amdgcn_fdot2(H4, wh##g##_4, pa##g, false);          \
        pb##g = __builtin_amdgcn_fdot2(H5, wh##g##_5, pb##g, false);          \
        pa##g = __builtin_amdgcn_fdot2(H6, wh##g##_6, pa##g, false);          \
        pb##g = __builtin_amdgcn_fdot2(H7, wh##g##_7, pb##g, false);          \
        float p##g = pa##g + pb##g;

#define STEP(RP, WP, TT)                                                      \
    {                                                                         \
        /* h reads FIRST; slice s = 16 halves = 32B = 2x b128 */              \
        const float4* hp = (const float4*)s_hh[RP];                           \
        const float4 hv0 = hp[s * 2 + 0];                                     \
        const float4 hv1 = hp[s * 2 + 1];                                     \
        /* prefetches behind h in the queue; consumed next step */            \
        const int   vtokB = s_tok[((TT) + 2) & (kT - 1)];                     \
        const float znext = s_projP[stokA * kG + tid];                        \
        const int   mskn  = (int)((smb >> stokA) & 1);                        \
        const v2h H0 = as_v2h(hv0.x), H1 = as_v2h(hv0.y);                     \
        const v2h H2 = as_v2h(hv0.z), H3 = as_v2h(hv0.w);                     \
        const v2h H4 = as_v2h(hv1.x), H5 = as_v2h(hv1.y);                     \
        const v2h H6 = as_v2h(hv1.z), H7 = as_v2h(hv1.w);                     \
        DOTG(0) DOTG(1) DOTG(2) DOTG(3)                                       \
        /* round 1: 2-lane sums over xor1 pairs, all gates */                 \
        p0 += dppf<kXor1>(p0); p1 += dppf<kXor1>(p1);                         \
        p2 += dppf<kXor1>(p2); p3 += dppf<kXor1>(p3);                         \
        /* select own pair-gate (xor2 partner has same s&1 -> gate-uniform) */\
        float X = (s & 1) ? p1 : p0;                                          \
        float Y = (s & 1) ? p3 : p2;                                          \
        X += dppf<kXor2>(X); Y += dppf<kXor2>(Y);                             \
        const float z = ((s & 2) ? Y : X) + zcur;                             \
        /* one activation per lane (own gate) */                              \
        const float e = exp2_f(z * aScale);                                   \
        const float r = fast_rcp(1.0f + e);                                   \
        const float a = fmaf(r, aMul, aAdd);                                  \
        /* quad broadcasts: gate q lives in lane q of the quad */             \
        const float ai = dppf<kBc0>(a);                                       \
        const float af = dppf<kBc1>(a);                                       \
        const float ag = dppf<kBc2>(a);                                       \
        const float ao = dppf<kBc3>(a);                                       \
        const float cn = fmaf(af, c, ai * ag);                                \
        const float hn = ao * tanh_f(cn);                                     \
        if (mskc) { c = cn; hreg = hn; }   /* uniform branch */               \
        if (s == 0) s_hh[WP][u] = (_Float16)hreg;                             \
        __syncthreads();                                                      \
        zcur = znext; mskc = mskn;                                            \
        stokA = __builtin_amdgcn_readfirstlane(vtokB);                        \
    }

    for (int t = 0; t < kT; t += 2) {
        STEP(0, 1, t)
        STEP(1, 0, t + 1)
    }
#undef STEP
#undef DOTG

    // ---- epilogue: owner lanes publish exact f32 h, then reduce ----
    if (s == 0) s_act[u] = hreg;          // full-precision final h
    __syncthreads();
    if (tid < kU) {
        float v = s_act[tid] * Wd[tid] + hb_val * Wd[kU + tid];
#pragma unroll
        for (int off = 32; off > 0; off >>= 1) v += __shfl_down(v, off, 64);
        if (tid == 0) out[b] = v + bd[0];
    }
}

extern "C" void kernel_launch(void* const* d_in, const int* in_sizes, int n_in,
                              void* d_out, int out_size, void* d_ws, size_t ws_size,
                              hipStream_t stream) {
    const int*   tokens = (const int*)d_in[0];
    const float* emb    = (const float*)d_in[1];
    const float* Wk_f   = (const float*)d_in[2];
    const float* Wr_f   = (const float*)d_in[3];
    const float* b_f    = (const float*)d_in[4];
    const float* Wk_b   = (const float*)d_in[5];
    // d_in[6] = Wr_b: unused (backward runs one step from h0=0)
    const float* b_b    = (const float*)d_in[7];
    const float* Wd     = (const float*)d_in[8];
    const float* bd     = (const float*)d_in[9];
    float* out = (float*)d_out;

    bilstm_last_kernel<<<kB, 256, 0, stream>>>(
        tokens, emb, Wk_f, Wr_f, b_f, Wk_b, b_b, Wd, bd, out);
}